// Round 1
// baseline (423.357 us; speedup 1.0000x reference)
//
#include <hip/hip_runtime.h>
#include <math.h>

typedef __attribute__((ext_vector_type(4))) float f32x4;
typedef __attribute__((ext_vector_type(8))) _Float16 f16x8;
typedef __attribute__((ext_vector_type(4))) _Float16 f16x4;

#define NB 128
#define NQ 128
#define NC 1024
#define ND 1024

// ---------------------------------------------------------------------------
// K1: logits[b][q][c] = 9 * lrelu(S) / (||lrelu(S)||_q + 1e-8),
//     S[c][q] = sum_d ctx[b][c][d] * qry[b][q][d]
// tile: 128c x 128q, K=1024, 4 waves (2x2), fp16 MFMA 16x16x32
// ---------------------------------------------------------------------------
__global__ __launch_bounds__(256, 2) void k1_logits(
    const float* __restrict__ qry, const float* __restrict__ ctx,
    float* __restrict__ logits)
{
  __shared__ _Float16 As[128][72];   // context rows (c), k contiguous, pad->72
  __shared__ _Float16 Bs[128][72];   // query rows (q)
  __shared__ float nrm[2][128];      // per-c-row sumsq partials (by wn)

  const int b  = blockIdx.y;
  const int c0 = blockIdx.x * 128;
  const int t  = threadIdx.x;
  const int lane = t & 63, wave = t >> 6;
  const int wm = wave >> 1, wn = wave & 1;
  const int g = lane >> 4, l15 = lane & 15;
  const int lrow = t >> 4, lcol = (t & 15) * 4;

  const float* ctxB = ctx + (size_t)b * NC * ND;
  const float* qB   = qry + (size_t)b * NQ * ND;

  f32x4 acc[4][4] = {};

  for (int k0 = 0; k0 < ND; k0 += 64) {
#pragma unroll
    for (int r = 0; r < 128; r += 16) {
      float4 va = *(const float4*)&ctxB[(size_t)(c0 + r + lrow) * ND + k0 + lcol];
      f16x4 ha = {(_Float16)va.x, (_Float16)va.y, (_Float16)va.z, (_Float16)va.w};
      *(f16x4*)&As[r + lrow][lcol] = ha;
      float4 vb = *(const float4*)&qB[(size_t)(r + lrow) * ND + k0 + lcol];
      f16x4 hb = {(_Float16)vb.x, (_Float16)vb.y, (_Float16)vb.z, (_Float16)vb.w};
      *(f16x4*)&Bs[r + lrow][lcol] = hb;
    }
    __syncthreads();
#pragma unroll
    for (int kk = 0; kk < 2; ++kk) {
      f16x8 af[4], bf[4];
#pragma unroll
      for (int m = 0; m < 4; ++m)
        af[m] = *(const f16x8*)&As[wm*64 + m*16 + l15][kk*32 + g*8];
#pragma unroll
      for (int n = 0; n < 4; ++n)
        bf[n] = *(const f16x8*)&Bs[wn*64 + n*16 + l15][kk*32 + g*8];
#pragma unroll
      for (int m = 0; m < 4; ++m)
#pragma unroll
        for (int n = 0; n < 4; ++n)
          acc[m][n] = __builtin_amdgcn_mfma_f32_16x16x32_f16(af[m], bf[n], acc[m][n], 0, 0, 0);
    }
    __syncthreads();
  }

  // leaky-relu + sum of squares over q (cols) for each c row
#pragma unroll
  for (int m = 0; m < 4; ++m) {
#pragma unroll
    for (int i = 0; i < 4; ++i) {
      float ss = 0.f;
#pragma unroll
      for (int n = 0; n < 4; ++n) {
        float v = acc[m][n][i];
        v = v > 0.f ? v : 0.1f * v;
        acc[m][n][i] = v;
        ss += v * v;
      }
      ss += __shfl_xor(ss, 1);
      ss += __shfl_xor(ss, 2);
      ss += __shfl_xor(ss, 4);
      ss += __shfl_xor(ss, 8);
      if (l15 == 0) nrm[wn][wm*64 + m*16 + g*4 + i] = ss;
    }
  }
  __syncthreads();

  float* attnB = logits + (size_t)b * NQ * NC;
#pragma unroll
  for (int m = 0; m < 4; ++m) {
    const int crow = wm*64 + m*16 + g*4;
    float sc[4];
#pragma unroll
    for (int i = 0; i < 4; ++i) {
      float nn = nrm[0][crow + i] + nrm[1][crow + i];
      sc[i] = 9.0f / (sqrtf(nn) + 1e-8f);
    }
#pragma unroll
    for (int n = 0; n < 4; ++n) {
      const int qq = wn*64 + n*16 + l15;
      float4 o;
      o.x = acc[m][n][0] * sc[0];
      o.y = acc[m][n][1] * sc[1];
      o.z = acc[m][n][2] * sc[2];
      o.w = acc[m][n][3] * sc[3];
      *(float4*)&attnB[(size_t)qq * NC + c0 + crow] = o;
    }
  }
}

// ---------------------------------------------------------------------------
// K2: in-place softmax over each (b,q) row of 1024 logits. 1 wave / row.
// ---------------------------------------------------------------------------
__global__ __launch_bounds__(256) void k2_softmax(float* __restrict__ attn)
{
  const int row  = blockIdx.x * 4 + (threadIdx.x >> 6);
  const int lane = threadIdx.x & 63;
  float* p = attn + (size_t)row * NC;

  float4 v[4];
  float mx = -1e30f;
#pragma unroll
  for (int j = 0; j < 4; ++j) {
    v[j] = *(const float4*)&p[lane * 4 + j * 256];
    mx = fmaxf(mx, fmaxf(fmaxf(v[j].x, v[j].y), fmaxf(v[j].z, v[j].w)));
  }
#pragma unroll
  for (int m = 1; m < 64; m <<= 1) mx = fmaxf(mx, __shfl_xor(mx, m));

  const float LOG2E = 1.4426950408889634f;
  float s = 0.f;
#pragma unroll
  for (int j = 0; j < 4; ++j) {
    v[j].x = exp2f((v[j].x - mx) * LOG2E);
    v[j].y = exp2f((v[j].y - mx) * LOG2E);
    v[j].z = exp2f((v[j].z - mx) * LOG2E);
    v[j].w = exp2f((v[j].w - mx) * LOG2E);
    s += v[j].x + v[j].y + v[j].z + v[j].w;
  }
#pragma unroll
  for (int m = 1; m < 64; m <<= 1) s += __shfl_xor(s, m);
  const float r = 1.0f / s;
#pragma unroll
  for (int j = 0; j < 4; ++j) {
    v[j].x *= r; v[j].y *= r; v[j].z *= r; v[j].w *= r;
    *(float4*)&p[lane * 4 + j * 256] = v[j];
  }
}

// ---------------------------------------------------------------------------
// K3: wcontext[b][q][d] = sum_c P[b][q][c] * ctx[b][c][d]
// tile: 128q x 128d, K(c)=1024.  A = P rows; B = ctx^T built via reg transpose.
// ---------------------------------------------------------------------------
__global__ __launch_bounds__(256, 2) void k3_wctx(
    const float* __restrict__ attn, const float* __restrict__ ctx,
    float* __restrict__ wout)
{
  __shared__ _Float16 Ps[128][72];   // P rows (q), k=c contiguous
  __shared__ _Float16 Cs[128][68];   // ctx^T rows (d), k=c contiguous, pad->68

  const int b  = blockIdx.y;
  const int d0 = blockIdx.x * 128;
  const int t  = threadIdx.x;
  const int lane = t & 63, wave = t >> 6;
  const int wm = wave >> 1, wn = wave & 1;
  const int g = lane >> 4, l15 = lane & 15;
  const int lrow = t >> 4, lcol = (t & 15) * 4;
  const int d4 = t & 31;      // d quad (0..31)
  const int cq0 = t >> 5;     // c quad base (0..7)

  const float* ctxB = ctx + (size_t)b * NC * ND;
  const float* pB   = attn + (size_t)b * NQ * NC;

  f32x4 acc[4][4] = {};

  for (int k0 = 0; k0 < NC; k0 += 64) {
#pragma unroll
    for (int r = 0; r < 128; r += 16) {
      float4 va = *(const float4*)&pB[(size_t)(r + lrow) * NC + k0 + lcol];
      f16x4 ha = {(_Float16)va.x, (_Float16)va.y, (_Float16)va.z, (_Float16)va.w};
      *(f16x4*)&Ps[r + lrow][lcol] = ha;
    }
#pragma unroll
    for (int pass = 0; pass < 2; ++pass) {
      const int cc = (cq0 + pass * 8) * 4;   // 0..60
      float4 ra = *(const float4*)&ctxB[(size_t)(k0 + cc + 0) * ND + d0 + d4 * 4];
      float4 rb = *(const float4*)&ctxB[(size_t)(k0 + cc + 1) * ND + d0 + d4 * 4];
      float4 rc = *(const float4*)&ctxB[(size_t)(k0 + cc + 2) * ND + d0 + d4 * 4];
      float4 rd = *(const float4*)&ctxB[(size_t)(k0 + cc + 3) * ND + d0 + d4 * 4];
      f16x4 w0 = {(_Float16)ra.x, (_Float16)rb.x, (_Float16)rc.x, (_Float16)rd.x};
      f16x4 w1 = {(_Float16)ra.y, (_Float16)rb.y, (_Float16)rc.y, (_Float16)rd.y};
      f16x4 w2 = {(_Float16)ra.z, (_Float16)rb.z, (_Float16)rc.z, (_Float16)rd.z};
      f16x4 w3 = {(_Float16)ra.w, (_Float16)rb.w, (_Float16)rc.w, (_Float16)rd.w};
      *(f16x4*)&Cs[d4 * 4 + 0][cc] = w0;
      *(f16x4*)&Cs[d4 * 4 + 1][cc] = w1;
      *(f16x4*)&Cs[d4 * 4 + 2][cc] = w2;
      *(f16x4*)&Cs[d4 * 4 + 3][cc] = w3;
    }
    __syncthreads();
#pragma unroll
    for (int kk = 0; kk < 2; ++kk) {
      f16x8 af[4], bf[4];
#pragma unroll
      for (int m = 0; m < 4; ++m)
        af[m] = *(const f16x8*)&Ps[wm*64 + m*16 + l15][kk*32 + g*8];
#pragma unroll
      for (int n = 0; n < 4; ++n) {
        const int rowd = wn*64 + n*16 + l15;
        f16x4 blo = *(const f16x4*)&Cs[rowd][kk*32 + g*8];
        f16x4 bhi = *(const f16x4*)&Cs[rowd][kk*32 + g*8 + 4];
        bf[n] = (f16x8){blo[0], blo[1], blo[2], blo[3],
                        bhi[0], bhi[1], bhi[2], bhi[3]};
      }
#pragma unroll
      for (int m = 0; m < 4; ++m)
#pragma unroll
        for (int n = 0; n < 4; ++n)
          acc[m][n] = __builtin_amdgcn_mfma_f32_16x16x32_f16(af[m], bf[n], acc[m][n], 0, 0, 0);
    }
    __syncthreads();
  }

  float* wB = wout + (size_t)b * NQ * ND;
#pragma unroll
  for (int m = 0; m < 4; ++m) {
    const int qrow = wm*64 + m*16 + g*4;
#pragma unroll
    for (int n = 0; n < 4; ++n) {
      const int dd = d0 + wn*64 + n*16 + l15;
#pragma unroll
      for (int i = 0; i < 4; ++i)
        wB[(size_t)(qrow + i) * ND + dd] = acc[m][n][i];
    }
  }
}

// ---------------------------------------------------------------------------
extern "C" void kernel_launch(void* const* d_in, const int* in_sizes, int n_in,
                              void* d_out, int out_size, void* d_ws, size_t ws_size,
                              hipStream_t stream)
{
  const float* qry = (const float*)d_in[0];
  const float* ctx = (const float*)d_in[1];
  float* out   = (float*)d_out;
  float* out_q = out;                                  // query passthrough
  float* out_w = out + (size_t)NB * NQ * ND;           // wcontext
  float* out_a = out + 2 * (size_t)NB * NQ * ND;       // attn (logits -> P)

  hipMemcpyAsync(out_q, qry, (size_t)NB * NQ * ND * sizeof(float),
                 hipMemcpyDeviceToDevice, stream);

  k1_logits<<<dim3(8, 128), 256, 0, stream>>>(qry, ctx, out_a);
  k2_softmax<<<dim3(4096), 256, 0, stream>>>(out_a);
  k3_wctx<<<dim3(8, 128), 256, 0, stream>>>(out_a, ctx, out_w);
}

// Round 3
// 365.733 us; speedup vs baseline: 1.1576x; 1.1576x over previous
//
#include <hip/hip_runtime.h>
#include <math.h>

typedef __attribute__((ext_vector_type(4))) float f32x4;
typedef __attribute__((ext_vector_type(8))) _Float16 f16x8;
typedef __attribute__((ext_vector_type(4))) _Float16 f16x4;

#define NB 128
#define NQ 128
#define NC 1024
#define ND 1024

static __device__ __forceinline__ f16x4 cvt4(float4 v) {
  auto lo = __builtin_amdgcn_cvt_pkrtz(v.x, v.y);   // __fp16 ext_vector(2)
  auto hi = __builtin_amdgcn_cvt_pkrtz(v.z, v.w);
  return (f16x4){(_Float16)lo[0], (_Float16)lo[1],
                 (_Float16)hi[0], (_Float16)hi[1]};
}
static __device__ __forceinline__ f16x4 cvtT(float a, float b, float c, float d) {
  auto lo = __builtin_amdgcn_cvt_pkrtz(a, b);
  auto hi = __builtin_amdgcn_cvt_pkrtz(c, d);
  return (f16x4){(_Float16)lo[0], (_Float16)lo[1],
                 (_Float16)hi[0], (_Float16)hi[1]};
}

// ---------------------------------------------------------------------------
// K1: logits[b][q][c] = 9 * lrelu(S) / (||lrelu(S)||_q + 1e-8),
//     S[c][q] = sum_d ctx[b][c][d] * qry[b][q][d]
// tile: 128c x 128q, K=1024, 4 waves (2x2), fp16 MFMA 16x16x32.
// Register double-buffered staging; also copies 1/8 of qry[b] to out_q.
// ---------------------------------------------------------------------------
__global__ __launch_bounds__(256, 2) void k1_logits(
    const float* __restrict__ qry, const float* __restrict__ ctx,
    float* __restrict__ logits, float* __restrict__ outq)
{
  __shared__ _Float16 As[128][72];   // context rows (c), k contiguous, pad->72
  __shared__ _Float16 Bs[128][72];   // query rows (q)
  __shared__ float nrm[2][128];      // per-c-row sumsq partials (by wn)

  const int b  = blockIdx.y;
  const int c0 = blockIdx.x * 128;
  const int t  = threadIdx.x;
  const int lane = t & 63, wave = t >> 6;
  const int wm = wave >> 1, wn = wave & 1;
  const int g = lane >> 4, l15 = lane & 15;
  const int lrow = t >> 4, lcol = (t & 15) * 4;

  const float* ctxB = ctx + (size_t)b * NC * ND;
  const float* qB   = qry + (size_t)b * NQ * ND;

  f32x4 acc[4][4] = {};
  float4 ra[8], rb[8];

  auto k1_load = [&](int k0) {
#pragma unroll
    for (int r = 0; r < 8; ++r) {
      ra[r] = *(const float4*)&ctxB[(size_t)(c0 + r*16 + lrow) * ND + k0 + lcol];
      rb[r] = *(const float4*)&qB[(size_t)(r*16 + lrow) * ND + k0 + lcol];
    }
  };

  k1_load(0);
  for (int k0 = 0; k0 < ND; k0 += 64) {
    // write phase: cvt + LDS store of the chunk loaded last iteration
#pragma unroll
    for (int r = 0; r < 8; ++r) {
      *(f16x4*)&As[r*16 + lrow][lcol] = cvt4(ra[r]);
      *(f16x4*)&Bs[r*16 + lrow][lcol] = cvt4(rb[r]);
    }
    __syncthreads();
    if (k0 + 64 < ND) k1_load(k0 + 64);   // prefetch overlaps MFMA below
#pragma unroll
    for (int kk = 0; kk < 2; ++kk) {
      f16x8 af[4], bf[4];
#pragma unroll
      for (int m = 0; m < 4; ++m)
        af[m] = *(const f16x8*)&As[wm*64 + m*16 + l15][kk*32 + g*8];
#pragma unroll
      for (int n = 0; n < 4; ++n)
        bf[n] = *(const f16x8*)&Bs[wn*64 + n*16 + l15][kk*32 + g*8];
#pragma unroll
      for (int m = 0; m < 4; ++m)
#pragma unroll
        for (int n = 0; n < 4; ++n)
          acc[m][n] = __builtin_amdgcn_mfma_f32_16x16x32_f16(af[m], bf[n], acc[m][n], 0, 0, 0);
    }
    __syncthreads();
  }

  // leaky-relu + sum of squares over q (cols) for each c row
#pragma unroll
  for (int m = 0; m < 4; ++m) {
#pragma unroll
    for (int i = 0; i < 4; ++i) {
      float ss = 0.f;
#pragma unroll
      for (int n = 0; n < 4; ++n) {
        float v = acc[m][n][i];
        v = v > 0.f ? v : 0.1f * v;
        acc[m][n][i] = v;
        ss += v * v;
      }
      ss += __shfl_xor(ss, 1);
      ss += __shfl_xor(ss, 2);
      ss += __shfl_xor(ss, 4);
      ss += __shfl_xor(ss, 8);
      if (l15 == 0) nrm[wn][wm*64 + m*16 + g*4 + i] = ss;
    }
  }
  __syncthreads();

  float* attnB = logits + (size_t)b * NQ * NC;
#pragma unroll
  for (int m = 0; m < 4; ++m) {
    const int crow = wm*64 + m*16 + g*4;
    float sc[4];
#pragma unroll
    for (int i = 0; i < 4; ++i) {
      float nn = nrm[0][crow + i] + nrm[1][crow + i];
      sc[i] = 9.0f / (sqrtf(nn) + 1e-8f);
    }
#pragma unroll
    for (int n = 0; n < 4; ++n) {
      const int qq = wn*64 + n*16 + l15;
      float4 o;
      o.x = acc[m][n][0] * sc[0];
      o.y = acc[m][n][1] * sc[1];
      o.z = acc[m][n][2] * sc[2];
      o.w = acc[m][n][3] * sc[3];
      *(float4*)&attnB[(size_t)qq * NC + c0 + crow] = o;
    }
  }

  // qry passthrough: this block copies its 1/8 chunk of qry[b] (L2-hot)
  {
    const int chunk = NQ * ND / 4 / 8;                 // float4s per block
    const float4* src = (const float4*)qB + blockIdx.x * chunk;
    float4* dst = (float4*)(outq + (size_t)b * NQ * ND) + blockIdx.x * chunk;
#pragma unroll
    for (int i = 0; i < chunk / 256; ++i)              // 16 iters
      dst[i*256 + t] = src[i*256 + t];
  }
}

// ---------------------------------------------------------------------------
// K2: in-place softmax over each (b,q) row of 1024 logits. 1 wave / row.
// ---------------------------------------------------------------------------
__global__ __launch_bounds__(256) void k2_softmax(float* __restrict__ attn)
{
  const int row  = blockIdx.x * 4 + (threadIdx.x >> 6);
  const int lane = threadIdx.x & 63;
  float* p = attn + (size_t)row * NC;

  float4 v[4];
  float mx = -1e30f;
#pragma unroll
  for (int j = 0; j < 4; ++j) {
    v[j] = *(const float4*)&p[lane * 4 + j * 256];
    mx = fmaxf(mx, fmaxf(fmaxf(v[j].x, v[j].y), fmaxf(v[j].z, v[j].w)));
  }
#pragma unroll
  for (int m = 1; m < 64; m <<= 1) mx = fmaxf(mx, __shfl_xor(mx, m));

  const float LOG2E = 1.4426950408889634f;
  float s = 0.f;
#pragma unroll
  for (int j = 0; j < 4; ++j) {
    v[j].x = exp2f((v[j].x - mx) * LOG2E);
    v[j].y = exp2f((v[j].y - mx) * LOG2E);
    v[j].z = exp2f((v[j].z - mx) * LOG2E);
    v[j].w = exp2f((v[j].w - mx) * LOG2E);
    s += v[j].x + v[j].y + v[j].z + v[j].w;
  }
#pragma unroll
  for (int m = 1; m < 64; m <<= 1) s += __shfl_xor(s, m);
  const float r = 1.0f / s;
#pragma unroll
  for (int j = 0; j < 4; ++j) {
    v[j].x *= r; v[j].y *= r; v[j].z *= r; v[j].w *= r;
    *(float4*)&p[lane * 4 + j * 256] = v[j];
  }
}

// ---------------------------------------------------------------------------
// K3: wcontext[b][q][d] = sum_c P[b][q][c] * ctx[b][c][d]
// tile: 128q x 128d, K(c)=1024.  A = P rows; B = ctx^T built via reg transpose.
// Register double-buffered staging.
// ---------------------------------------------------------------------------
__global__ __launch_bounds__(256, 2) void k3_wctx(
    const float* __restrict__ attn, const float* __restrict__ ctx,
    float* __restrict__ wout)
{
  __shared__ _Float16 Ps[128][72];   // P rows (q), k=c contiguous
  __shared__ _Float16 Cs[128][68];   // ctx^T rows (d), k=c contiguous, pad->68

  const int b  = blockIdx.y;
  const int d0 = blockIdx.x * 128;
  const int t  = threadIdx.x;
  const int lane = t & 63, wave = t >> 6;
  const int wm = wave >> 1, wn = wave & 1;
  const int g = lane >> 4, l15 = lane & 15;
  const int lrow = t >> 4, lcol = (t & 15) * 4;
  const int d4 = t & 31;      // d quad (0..31)
  const int cq0 = t >> 5;     // c quad base (0..7)

  const float* ctxB = ctx + (size_t)b * NC * ND;
  const float* pB   = attn + (size_t)b * NQ * NC;

  f32x4 acc[4][4] = {};
  float4 pa[8], rc[8];

  auto k3_load = [&](int k0) {
#pragma unroll
    for (int r = 0; r < 8; ++r)
      pa[r] = *(const float4*)&pB[(size_t)(r*16 + lrow) * NC + k0 + lcol];
#pragma unroll
    for (int p = 0; p < 2; ++p) {
      const int cc = (cq0 + p*8) * 4;
#pragma unroll
      for (int j = 0; j < 4; ++j)
        rc[p*4 + j] = *(const float4*)&ctxB[(size_t)(k0 + cc + j) * ND + d0 + d4*4];
    }
  };

  k3_load(0);
  for (int k0 = 0; k0 < NC; k0 += 64) {
    // write phase
#pragma unroll
    for (int r = 0; r < 8; ++r)
      *(f16x4*)&Ps[r*16 + lrow][lcol] = cvt4(pa[r]);
#pragma unroll
    for (int p = 0; p < 2; ++p) {
      const int cc = (cq0 + p*8) * 4;
      float4 r0 = rc[p*4+0], r1 = rc[p*4+1], r2 = rc[p*4+2], r3 = rc[p*4+3];
      *(f16x4*)&Cs[d4*4 + 0][cc] = cvtT(r0.x, r1.x, r2.x, r3.x);
      *(f16x4*)&Cs[d4*4 + 1][cc] = cvtT(r0.y, r1.y, r2.y, r3.y);
      *(f16x4*)&Cs[d4*4 + 2][cc] = cvtT(r0.z, r1.z, r2.z, r3.z);
      *(f16x4*)&Cs[d4*4 + 3][cc] = cvtT(r0.w, r1.w, r2.w, r3.w);
    }
    __syncthreads();
    if (k0 + 64 < NC) k3_load(k0 + 64);   // prefetch overlaps MFMA below
#pragma unroll
    for (int kk = 0; kk < 2; ++kk) {
      f16x8 af[4], bf[4];
#pragma unroll
      for (int m = 0; m < 4; ++m)
        af[m] = *(const f16x8*)&Ps[wm*64 + m*16 + l15][kk*32 + g*8];
#pragma unroll
      for (int n = 0; n < 4; ++n) {
        const int rowd = wn*64 + n*16 + l15;
        f16x4 blo = *(const f16x4*)&Cs[rowd][kk*32 + g*8];
        f16x4 bhi = *(const f16x4*)&Cs[rowd][kk*32 + g*8 + 4];
        bf[n] = (f16x8){blo[0], blo[1], blo[2], blo[3],
                        bhi[0], bhi[1], bhi[2], bhi[3]};
      }
#pragma unroll
      for (int m = 0; m < 4; ++m)
#pragma unroll
        for (int n = 0; n < 4; ++n)
          acc[m][n] = __builtin_amdgcn_mfma_f32_16x16x32_f16(af[m], bf[n], acc[m][n], 0, 0, 0);
    }
    __syncthreads();
  }

  float* wB = wout + (size_t)b * NQ * ND;
#pragma unroll
  for (int m = 0; m < 4; ++m) {
    const int qrow = wm*64 + m*16 + g*4;
#pragma unroll
    for (int n = 0; n < 4; ++n) {
      const int dd = d0 + wn*64 + n*16 + l15;
#pragma unroll
      for (int i = 0; i < 4; ++i)
        wB[(size_t)(qrow + i) * ND + dd] = acc[m][n][i];
    }
  }
}

// ---------------------------------------------------------------------------
extern "C" void kernel_launch(void* const* d_in, const int* in_sizes, int n_in,
                              void* d_out, int out_size, void* d_ws, size_t ws_size,
                              hipStream_t stream)
{
  const float* qry = (const float*)d_in[0];
  const float* ctx = (const float*)d_in[1];
  float* out   = (float*)d_out;
  float* out_q = out;                                  // query passthrough
  float* out_w = out + (size_t)NB * NQ * ND;           // wcontext
  float* out_a = out + 2 * (size_t)NB * NQ * ND;       // attn (logits -> P)

  k1_logits<<<dim3(8, 128), 256, 0, stream>>>(qry, ctx, out_a, out_q);
  k2_softmax<<<dim3(4096), 256, 0, stream>>>(out_a);
  k3_wctx<<<dim3(8, 128), 256, 0, stream>>>(out_a, ctx, out_w);
}

// Round 4
// 334.165 us; speedup vs baseline: 1.2669x; 1.0945x over previous
//
#include <hip/hip_runtime.h>
#include <math.h>

typedef __attribute__((ext_vector_type(4))) float f32x4;
typedef __attribute__((ext_vector_type(8))) _Float16 f16x8;
typedef __attribute__((ext_vector_type(4))) _Float16 f16x4;

#define NB 128
#define NQ 128
#define NC 1024
#define ND 1024

static __device__ __forceinline__ f16x4 cvt4(float4 v) {
  auto lo = __builtin_amdgcn_cvt_pkrtz(v.x, v.y);   // __fp16 ext_vector(2)
  auto hi = __builtin_amdgcn_cvt_pkrtz(v.z, v.w);
  return (f16x4){(_Float16)lo[0], (_Float16)lo[1],
                 (_Float16)hi[0], (_Float16)hi[1]};
}
static __device__ __forceinline__ f16x4 cvtT(float a, float b, float c, float d) {
  auto lo = __builtin_amdgcn_cvt_pkrtz(a, b);
  auto hi = __builtin_amdgcn_cvt_pkrtz(c, d);
  return (f16x4){(_Float16)lo[0], (_Float16)lo[1],
                 (_Float16)hi[0], (_Float16)hi[1]};
}

// XCD-grouping remap: linear L = x + 8*y, XCD = L%8 (8 XCDs, round-robin).
// b = (L&7) + 8*(L>>6), tile = (L>>3)&7  ->  all 8 tile-blocks of a given b
// are L≡b (mod 8): same XCD, adjacent in dispatch -> shared tensor (qry[b] /
// P[b]) is fetched into that XCD's L2 once and hit 7 times.
static __device__ __forceinline__ void remap(int& b, int& tile) {
  const int L = blockIdx.x + ((int)gridDim.x) * blockIdx.y;
  b = (L & 7) + 8 * (L >> 6);
  tile = (L >> 3) & 7;
}

// ---------------------------------------------------------------------------
// K1: logits[b][q][c] = 9 * lrelu(S) / (||lrelu(S)||_q + 1e-8),
//     S[c][q] = sum_d ctx[b][c][d] * qry[b][q][d]
// tile: 128c x 128q, K=1024, 4 waves (2x2), fp16 MFMA 16x16x32.
// Register double-buffered staging; also copies 1/8 of qry[b] to out_q.
// ---------------------------------------------------------------------------
__global__ __launch_bounds__(256, 2) void k1_logits(
    const float* __restrict__ qry, const float* __restrict__ ctx,
    float* __restrict__ logits, float* __restrict__ outq)
{
  __shared__ _Float16 As[128][72];   // context rows (c), k contiguous, pad->72
  __shared__ _Float16 Bs[128][72];   // query rows (q)
  __shared__ float nrm[2][128];      // per-c-row sumsq partials (by wn)

  int b, ct;
  remap(b, ct);
  const int c0 = ct * 128;
  const int t  = threadIdx.x;
  const int lane = t & 63, wave = t >> 6;
  const int wm = wave >> 1, wn = wave & 1;
  const int g = lane >> 4, l15 = lane & 15;
  const int lrow = t >> 4, lcol = (t & 15) * 4;

  const float* ctxB = ctx + (size_t)b * NC * ND;
  const float* qB   = qry + (size_t)b * NQ * ND;

  f32x4 acc[4][4] = {};
  float4 ra[8], rb[8];

  auto k1_load = [&](int k0) {
#pragma unroll
    for (int r = 0; r < 8; ++r) {
      ra[r] = *(const float4*)&ctxB[(size_t)(c0 + r*16 + lrow) * ND + k0 + lcol];
      rb[r] = *(const float4*)&qB[(size_t)(r*16 + lrow) * ND + k0 + lcol];
    }
  };

  k1_load(0);
  for (int k0 = 0; k0 < ND; k0 += 64) {
    // write phase: cvt + LDS store of the chunk loaded last iteration
#pragma unroll
    for (int r = 0; r < 8; ++r) {
      *(f16x4*)&As[r*16 + lrow][lcol] = cvt4(ra[r]);
      *(f16x4*)&Bs[r*16 + lrow][lcol] = cvt4(rb[r]);
    }
    __syncthreads();
    if (k0 + 64 < ND) k1_load(k0 + 64);   // prefetch overlaps MFMA below
#pragma unroll
    for (int kk = 0; kk < 2; ++kk) {
      f16x8 af[4], bf[4];
#pragma unroll
      for (int m = 0; m < 4; ++m)
        af[m] = *(const f16x8*)&As[wm*64 + m*16 + l15][kk*32 + g*8];
#pragma unroll
      for (int n = 0; n < 4; ++n)
        bf[n] = *(const f16x8*)&Bs[wn*64 + n*16 + l15][kk*32 + g*8];
#pragma unroll
      for (int m = 0; m < 4; ++m)
#pragma unroll
        for (int n = 0; n < 4; ++n)
          acc[m][n] = __builtin_amdgcn_mfma_f32_16x16x32_f16(af[m], bf[n], acc[m][n], 0, 0, 0);
    }
    __syncthreads();
  }

  // leaky-relu + sum of squares over q (cols) for each c row
#pragma unroll
  for (int m = 0; m < 4; ++m) {
#pragma unroll
    for (int i = 0; i < 4; ++i) {
      float ss = 0.f;
#pragma unroll
      for (int n = 0; n < 4; ++n) {
        float v = acc[m][n][i];
        v = v > 0.f ? v : 0.1f * v;
        acc[m][n][i] = v;
        ss += v * v;
      }
      ss += __shfl_xor(ss, 1);
      ss += __shfl_xor(ss, 2);
      ss += __shfl_xor(ss, 4);
      ss += __shfl_xor(ss, 8);
      if (l15 == 0) nrm[wn][wm*64 + m*16 + g*4 + i] = ss;
    }
  }
  __syncthreads();

  float* attnB = logits + (size_t)b * NQ * NC;
#pragma unroll
  for (int m = 0; m < 4; ++m) {
    const int crow = wm*64 + m*16 + g*4;
    float sc[4];
#pragma unroll
    for (int i = 0; i < 4; ++i) {
      float nn = nrm[0][crow + i] + nrm[1][crow + i];
      sc[i] = 9.0f / (sqrtf(nn) + 1e-8f);
    }
#pragma unroll
    for (int n = 0; n < 4; ++n) {
      const int qq = wn*64 + n*16 + l15;
      float4 o;
      o.x = acc[m][n][0] * sc[0];
      o.y = acc[m][n][1] * sc[1];
      o.z = acc[m][n][2] * sc[2];
      o.w = acc[m][n][3] * sc[3];
      *(float4*)&attnB[(size_t)qq * NC + c0 + crow] = o;
    }
  }

  // qry passthrough: this block copies its 1/8 chunk of qry[b] (L2-hot)
  {
    const int chunk = NQ * ND / 4 / 8;                 // float4s per block
    const float4* src = (const float4*)qB + ct * chunk;
    float4* dst = (float4*)(outq + (size_t)b * NQ * ND) + ct * chunk;
#pragma unroll
    for (int i = 0; i < chunk / 256; ++i)              // 16 iters
      dst[i*256 + t] = src[i*256 + t];
  }
}

// ---------------------------------------------------------------------------
// K2: in-place softmax over each (b,q) row of 1024 logits. 1 wave / row.
// ---------------------------------------------------------------------------
__global__ __launch_bounds__(256) void k2_softmax(float* __restrict__ attn)
{
  const int row  = blockIdx.x * 4 + (threadIdx.x >> 6);
  const int lane = threadIdx.x & 63;
  float* p = attn + (size_t)row * NC;

  float4 v[4];
  float mx = -1e30f;
#pragma unroll
  for (int j = 0; j < 4; ++j) {
    v[j] = *(const float4*)&p[lane * 4 + j * 256];
    mx = fmaxf(mx, fmaxf(fmaxf(v[j].x, v[j].y), fmaxf(v[j].z, v[j].w)));
  }
#pragma unroll
  for (int m = 1; m < 64; m <<= 1) mx = fmaxf(mx, __shfl_xor(mx, m));

  const float LOG2E = 1.4426950408889634f;
  float s = 0.f;
#pragma unroll
  for (int j = 0; j < 4; ++j) {
    v[j].x = exp2f((v[j].x - mx) * LOG2E);
    v[j].y = exp2f((v[j].y - mx) * LOG2E);
    v[j].z = exp2f((v[j].z - mx) * LOG2E);
    v[j].w = exp2f((v[j].w - mx) * LOG2E);
    s += v[j].x + v[j].y + v[j].z + v[j].w;
  }
#pragma unroll
  for (int m = 1; m < 64; m <<= 1) s += __shfl_xor(s, m);
  const float r = 1.0f / s;
#pragma unroll
  for (int j = 0; j < 4; ++j) {
    v[j].x *= r; v[j].y *= r; v[j].z *= r; v[j].w *= r;
    *(float4*)&p[lane * 4 + j * 256] = v[j];
  }
}

// ---------------------------------------------------------------------------
// K3: wcontext[b][q][d] = sum_c P[b][q][c] * ctx[b][c][d]
// tile: 128q x 128d, K(c)=1024.  A = P rows; B = ctx^T built via reg transpose.
// Register double-buffered staging.
// ---------------------------------------------------------------------------
__global__ __launch_bounds__(256, 2) void k3_wctx(
    const float* __restrict__ attn, const float* __restrict__ ctx,
    float* __restrict__ wout)
{
  __shared__ _Float16 Ps[128][72];   // P rows (q), k=c contiguous
  __shared__ _Float16 Cs[128][68];   // ctx^T rows (d), k=c contiguous, pad->68

  int b, dt;
  remap(b, dt);
  const int d0 = dt * 128;
  const int t  = threadIdx.x;
  const int lane = t & 63, wave = t >> 6;
  const int wm = wave >> 1, wn = wave & 1;
  const int g = lane >> 4, l15 = lane & 15;
  const int lrow = t >> 4, lcol = (t & 15) * 4;
  const int d4 = t & 31;      // d quad (0..31)
  const int cq0 = t >> 5;     // c quad base (0..7)

  const float* ctxB = ctx + (size_t)b * NC * ND;
  const float* pB   = attn + (size_t)b * NQ * NC;

  f32x4 acc[4][4] = {};
  float4 pa[8], rc[8];

  auto k3_load = [&](int k0) {
#pragma unroll
    for (int r = 0; r < 8; ++r)
      pa[r] = *(const float4*)&pB[(size_t)(r*16 + lrow) * NC + k0 + lcol];
#pragma unroll
    for (int p = 0; p < 2; ++p) {
      const int cc = (cq0 + p*8) * 4;
#pragma unroll
      for (int j = 0; j < 4; ++j)
        rc[p*4 + j] = *(const float4*)&ctxB[(size_t)(k0 + cc + j) * ND + d0 + d4*4];
    }
  };

  k3_load(0);
  for (int k0 = 0; k0 < NC; k0 += 64) {
    // write phase
#pragma unroll
    for (int r = 0; r < 8; ++r)
      *(f16x4*)&Ps[r*16 + lrow][lcol] = cvt4(pa[r]);
#pragma unroll
    for (int p = 0; p < 2; ++p) {
      const int cc = (cq0 + p*8) * 4;
      float4 r0 = rc[p*4+0], r1 = rc[p*4+1], r2 = rc[p*4+2], r3 = rc[p*4+3];
      *(f16x4*)&Cs[d4*4 + 0][cc] = cvtT(r0.x, r1.x, r2.x, r3.x);
      *(f16x4*)&Cs[d4*4 + 1][cc] = cvtT(r0.y, r1.y, r2.y, r3.y);
      *(f16x4*)&Cs[d4*4 + 2][cc] = cvtT(r0.z, r1.z, r2.z, r3.z);
      *(f16x4*)&Cs[d4*4 + 3][cc] = cvtT(r0.w, r1.w, r2.w, r3.w);
    }
    __syncthreads();
    if (k0 + 64 < NC) k3_load(k0 + 64);   // prefetch overlaps MFMA below
#pragma unroll
    for (int kk = 0; kk < 2; ++kk) {
      f16x8 af[4], bf[4];
#pragma unroll
      for (int m = 0; m < 4; ++m)
        af[m] = *(const f16x8*)&Ps[wm*64 + m*16 + l15][kk*32 + g*8];
#pragma unroll
      for (int n = 0; n < 4; ++n) {
        const int rowd = wn*64 + n*16 + l15;
        f16x4 blo = *(const f16x4*)&Cs[rowd][kk*32 + g*8];
        f16x4 bhi = *(const f16x4*)&Cs[rowd][kk*32 + g*8 + 4];
        bf[n] = (f16x8){blo[0], blo[1], blo[2], blo[3],
                        bhi[0], bhi[1], bhi[2], bhi[3]};
      }
#pragma unroll
      for (int m = 0; m < 4; ++m)
#pragma unroll
        for (int n = 0; n < 4; ++n)
          acc[m][n] = __builtin_amdgcn_mfma_f32_16x16x32_f16(af[m], bf[n], acc[m][n], 0, 0, 0);
    }
    __syncthreads();
  }

  float* wB = wout + (size_t)b * NQ * ND;
#pragma unroll
  for (int m = 0; m < 4; ++m) {
    const int qrow = wm*64 + m*16 + g*4;
#pragma unroll
    for (int n = 0; n < 4; ++n) {
      const int dd = d0 + wn*64 + n*16 + l15;
#pragma unroll
      for (int i = 0; i < 4; ++i)
        wB[(size_t)(qrow + i) * ND + dd] = acc[m][n][i];
    }
  }
}

// ---------------------------------------------------------------------------
extern "C" void kernel_launch(void* const* d_in, const int* in_sizes, int n_in,
                              void* d_out, int out_size, void* d_ws, size_t ws_size,
                              hipStream_t stream)
{
  const float* qry = (const float*)d_in[0];
  const float* ctx = (const float*)d_in[1];
  float* out   = (float*)d_out;
  float* out_q = out;                                  // query passthrough
  float* out_w = out + (size_t)NB * NQ * ND;           // wcontext
  float* out_a = out + 2 * (size_t)NB * NQ * ND;       // attn (logits -> P)

  k1_logits<<<dim3(8, 128), 256, 0, stream>>>(qry, ctx, out_a, out_q);
  k2_softmax<<<dim3(4096), 256, 0, stream>>>(out_a);
  k3_wctx<<<dim3(8, 128), 256, 0, stream>>>(out_a, ctx, out_w);
}